// Round 10
// baseline (685.982 us; speedup 1.0000x reference)
//
#include <hip/hip_runtime.h>

// SDE scan: B=2048 rows, T=512 steps, FS=32, FA=16, H=64.
// One wave per batch row; T-loop in-kernel (recurrence is per-row).
// R10: DS-THROUGHPUT attack. R3/R7/R9 all pin at ~2100cy/step regardless of
//     VALU issue count -> LDS unit (per-CU, shared by 8 waves) is the wall:
//     8 waves x 31 DS ops x ~9cy ~= 2200cy = measured. Fix: move L1 operand
//     broadcast from LDS to readlane->SGPR (VALU has 47% idle slots):
//       - x: 32 readlanes from x_cur (also removes x LDS round trip from
//         the serial chain; xbuf deleted).
//       - a: 16 readlanes from the prefetched aq quad component (R2-proven;
//         abuf deleted).
//       - L1 = R3's scalar dual chains (SGPR operand on v_fmac, no movs).
//     L2 unchanged from R7 (sigma LDS layout, pk FMA, 16 ds_read_b128 -
//     irreducible h-broadcast) + permlane32_swap + eps pre-scale.
//     DS ops/wave-step: 31 -> 18. Predicted 310-380us if DS-bound model holds.
//     Bit-exact vs R3/R7/R9: absmax must stay EXACTLY 0.0078125.

#define SQRT_DT_F 0.22360679774997896f

typedef float v2f __attribute__((ext_vector_type(2)));
typedef float v4f __attribute__((ext_vector_type(4)));
typedef int   v2i __attribute__((ext_vector_type(2)));

// Packed 2x fp32 FMA: per-element fmaf semantics; lowers to v_pk_fma_f32.
#define PK(acc, s, w) (acc) = __builtin_elementwise_fma((s), (w), (acc))

__device__ __forceinline__ float fast_tanh(float y) {
    // tanh(y) = 1 - 2/(exp(2y)+1); stable at both extremes
    float e = __expf(2.0f * y);
    return 1.0f - 2.0f / (e + 1.0f);
}

__device__ __forceinline__ float rl(float v, int l) {
    // readlane -> SGPR broadcast (free operand on consuming v_fma)
    return __int_as_float(__builtin_amdgcn_readlane(__float_as_int(v), l));
}

__device__ __forceinline__ void wave_sync() {
    // Single-wave block: DS pipe is in-order within a wave; we only need to
    // stop the compiler moving DS ops across this point. Everything else
    // (VALU/SALU/VMEM/trans) may cross freely.
    __builtin_amdgcn_fence(__ATOMIC_SEQ_CST, "wavefront");
    __builtin_amdgcn_sched_barrier(0x047F);
}

__global__ __launch_bounds__(64, 2)
void sde_kernel(const float* __restrict__ in_signal,   // (B,16,512)
                const float* __restrict__ x0v,         // (B,32)
                const float* __restrict__ noise,       // (511,B,32)
                const float* __restrict__ Wf1, const float* __restrict__ bf1,
                const float* __restrict__ Wf2, const float* __restrict__ bf2,
                const float* __restrict__ Wg1, const float* __restrict__ bg1,
                const float* __restrict__ Wg2, const float* __restrict__ bg2,
                float* __restrict__ out)               // (B,32,512)
{
    const int lane = threadIdx.x;   // 0..63
    const int b    = blockIdx.x;    // batch row

    __shared__ __align__(16) float hbuf[2][128];   // [parity][hf(64), hg(64)], sigma-permuted

    // ---- L1 weights -> scalar registers (R3 layout; one-time, coalesced) ----
    float w1f[48], w1g[48];
#pragma unroll
    for (int k = 0; k < 48; ++k) {
        w1f[k] = Wf1[k * 64 + lane];
        w1g[k] = Wg1[k * 64 + lane];
    }
    // L2 weights as pk pairs: pair (g,i) covers h indices (8g+i, 8g+4+i)
    // matching the (acc2a, acc2b) chains.
    v2f w2v[32];
    const float* W2p = (lane < 32) ? (Wf2 + lane) : (Wg2 + (lane - 32));
#pragma unroll
    for (int g = 0; g < 8; ++g)
#pragma unroll
        for (int i = 0; i < 4; ++i)
            w2v[g * 4 + i] = v2f{W2p[(8 * g + i) * 32], W2p[(8 * g + 4 + i) * 32]};

    const float b1f = bf1[lane];
    const float b1g = bg1[lane];
    const float b2  = (lane < 32) ? bf2[lane] : bg2[lane - 32];

    // ---- state: x_{lane&31} identical in both wave halves (registers only) ----
    float x_cur = x0v[b * 32 + (lane & 31)];
    float xq[4];
    xq[0] = x_cur;

    // sigma: position of h_j inside its 8-block so that (j, j+4) pairs are
    // adjacent in LDS. sigma(8g+r) = 8g + ((r&3)<<1 | r>>2).
    const int sig = (lane & ~7) | ((lane & 3) << 1) | ((lane >> 2) & 1);
    float* hw0 = &hbuf[0][sig];                          // hf slot, parity 0
    float* hw1 = &hbuf[1][sig];                          // parity 1
    const float* hsrc0 = hbuf[0] + ((lane >> 5) << 6);   // hf or hg, parity 0
    const float* hsrc1 = hbuf[1] + ((lane >> 5) << 6);   // parity 1
    const float* a_base = in_signal + ((size_t)(b * 16 + (lane & 15)) << 9);
    const float* noise_lane = noise + (size_t)b * 32 + (lane & 31);
    float* out_ptr = out + ((size_t)b * 32 + (lane & 31)) * 512;

    // prefetch eps two steps ahead, pre-scaled by sqrt(dt) at load
    float eps_c = noise_lane[0] * SQRT_DT_F;             // t = 0
    float eps_n = noise_lane[65536] * SQRT_DT_F;         // t = 1

    // a quad for t = 0..3 (lane k<16 holds feature k; dup in other lanes)
    float4 aq = *(const float4*)(a_base);

#define STEP(tt) do {                                                           \
    const int t_ = tq4 + (tt);                                                  \
    /* prefetch eps for step t+2 (~2 steps of latency cover), pre-scaled */     \
    int tf_ = t_ + 2; if (tf_ > 510) tf_ = 510;                                 \
    float eps_f = noise_lane[(size_t)tf_ << 16] * SQRT_DT_F;                    \
    const float ac_ = ((tt) == 0 ? aq.x : (tt) == 1 ? aq.y                      \
                      : (tt) == 2 ? aq.z : aq.w);                               \
    /* layer 1: lane j -> hf_j, hg_j ; operands via readlane->SGPR (no DS). */  \
    /* Dual scalar chains == pk .x/.y lanes == R3: bit-exact. */                \
    float accf0 = b1f, accf1 = 0.f, accg0 = b1g, accg1 = 0.f;                   \
    _Pragma("unroll")                                                           \
    for (int k = 0; k < 16; k += 2) {                                           \
        float s0 = rl(ac_, k), s1 = rl(ac_, k + 1);                             \
        accf0 = fmaf(s0, w1f[k],     accf0); accg0 = fmaf(s0, w1g[k],     accg0);\
        accf1 = fmaf(s1, w1f[k + 1], accf1); accg1 = fmaf(s1, w1g[k + 1], accg1);\
    }                                                                           \
    _Pragma("unroll")                                                           \
    for (int i = 0; i < 32; i += 2) {                                           \
        float s0 = rl(x_cur, i), s1 = rl(x_cur, i + 1);                         \
        accf0 = fmaf(s0, w1f[16 + i], accf0); accg0 = fmaf(s0, w1g[16 + i], accg0);\
        accf1 = fmaf(s1, w1f[17 + i], accf1); accg1 = fmaf(s1, w1g[17 + i], accg1);\
    }                                                                           \
    float hfv = fast_tanh(accf0 + accf1);                                       \
    float hgv = fast_tanh(accg0 + accg1);                                       \
    {   /* sigma-permuted h write: conflict-free bijection per 8-block */       \
        float* hw_ = ((tt) & 1) ? hw1 : hw0;                                    \
        hw_[0]  = hfv;                                                          \
        hw_[64] = hgv;                                                          \
    }                                                                           \
    wave_sync();                                                                \
    /* layer 2: lanes 0-31 drift_i (hf), lanes 32-63 diff-pre_i (hg) */         \
    {                                                                           \
        const float* hs_ = ((tt) & 1) ? hsrc1 : hsrc0;                          \
        v2f a2 = v2f{b2, 0.f};   /* pk lanes = original (acc2a, acc2b) */       \
        _Pragma("unroll")                                                       \
        for (int g = 0; g < 8; ++g) {                                           \
            const v4f qa = *(const v4f*)&hs_[g * 8];                            \
            const v4f qb = *(const v4f*)&hs_[g * 8 + 4];                        \
            v2f p0 = qa.xy, p1 = qa.zw, p2 = qb.xy, p3 = qb.zw;                 \
            PK(a2, p0, w2v[g * 4 + 0]);                                         \
            PK(a2, p1, w2v[g * 4 + 1]);                                         \
            PK(a2, p2, w2v[g * 4 + 2]);                                         \
            PK(a2, p3, w2v[g * 4 + 3]);                                         \
        }                                                                       \
        float acc2 = a2.x + a2.y;                                               \
        /* swap halves in-register (VALU, no DS): drift/gpre to all lanes */    \
        v2i pr = __builtin_amdgcn_permlane32_swap(                              \
            __float_as_int(acc2), __float_as_int(acc2), false, false);          \
        const float drift = __int_as_float(pr.x);                               \
        const float gpre  = __int_as_float(pr.y);                               \
        float xi = fmaf(gpre, eps_c, drift);                                    \
        xi = fminf(5.0f, fmaxf(-5.0f, xi));                                     \
        x_cur = xi;                                                             \
        xq[((tt) + 1) & 3] = xi;                                                \
        if ((tt) == 2) {                                                        \
            if (lane < 32)                                                      \
                *(float4*)(out_ptr + tq4) =                                     \
                    make_float4(xq[0], xq[1], xq[2], xq[3]);                    \
        }                                                                       \
    }                                                                           \
    wave_sync();                                                                \
    eps_c = eps_n; eps_n = eps_f;                                               \
} while (0)

    // main: t = 0..507 (127 quads)
    for (int tq = 0; tq < 127; ++tq) {
        const int tq4 = tq * 4;
        float4 aq_n = *(const float4*)(a_base + tq4 + 4);   // quad tq+1 (<=508)
        STEP(0); STEP(1); STEP(2); STEP(3);
        aq = aq_n;
    }
    // tail: t = 508, 509, 510  (store of [508..511] fires at tt==2)
    {
        const int tq4 = 508;
        STEP(0); STEP(1); STEP(2);
    }
#undef STEP
}

extern "C" void kernel_launch(void* const* d_in, const int* in_sizes, int n_in,
                              void* d_out, int out_size, void* d_ws, size_t ws_size,
                              hipStream_t stream) {
    // inputs: 0 ts(unused), 1 in_signal, 2 x0, 3 noise, 4 Wf1, 5 bf1, 6 Wf2,
    //         7 bf2, 8 Wg1, 9 bg1, 10 Wg2, 11 bg2
    const float* in_signal = (const float*)d_in[1];
    const float* x0v   = (const float*)d_in[2];
    const float* noise = (const float*)d_in[3];
    const float* Wf1 = (const float*)d_in[4];
    const float* bf1 = (const float*)d_in[5];
    const float* Wf2 = (const float*)d_in[6];
    const float* bf2 = (const float*)d_in[7];
    const float* Wg1 = (const float*)d_in[8];
    const float* bg1 = (const float*)d_in[9];
    const float* Wg2 = (const float*)d_in[10];
    const float* bg2 = (const float*)d_in[11];
    float* out = (float*)d_out;

    hipLaunchKernelGGL(sde_kernel, dim3(2048), dim3(64), 0, stream,
                       in_signal, x0v, noise, Wf1, bf1, Wf2, bf2,
                       Wg1, bg1, Wg2, bg2, out);
}

// Round 11
// 581.048 us; speedup vs baseline: 1.1806x; 1.1806x over previous
//
#include <hip/hip_runtime.h>

// SDE scan: B=2048 rows, T=512 steps, FS=32, FA=16, H=64.
// One wave per batch row; T-loop in-kernel (recurrence is per-row).
// R11 = R3-exact restore (session champion, 440.8us dispatch).
// Session conclusion: this family is LDS-instruction-throughput-bound:
//   8 waves/CU x ~31 DS instr/step x ~8.5cy ~= 2100cy/step = the measured
//   wall of R3/R7/R9 (2067/2127/2184cy); VALUBusy == VALU_issue/DS_floor in
//   every variant (91%/54.5%/53% -- exact). R3 co-saturates VALU at 91% of
//   the DS ceiling -> optimal balance. Proven-negative alternatives:
//   readlane broadcast (+500cy, R2/R10), cross-wave split (2.6x, R8),
//   pk-FMA (null -- frees VALU below the DS floor, R7/R9), occupancy/attr
//   games (R4/R5). DS count 31 is structural: (16a+32x+64h)/4 + writes.

#define SQRT_DT_F 0.22360679774997896f

__device__ __forceinline__ float fast_tanh(float y) {
    // tanh(y) = 1 - 2/(exp(2y)+1); stable at both extremes
    float e = __expf(2.0f * y);
    return 1.0f - 2.0f / (e + 1.0f);
}

__device__ __forceinline__ void wave_sync() {
    // Single-wave block: DS pipe is in-order within a wave; we only need to
    // stop the compiler moving DS ops across this point. Everything else
    // (VALU/SALU/VMEM/trans) may cross freely.
    __builtin_amdgcn_fence(__ATOMIC_SEQ_CST, "wavefront");
    __builtin_amdgcn_sched_barrier(0x047F);
}

__global__ __launch_bounds__(64, 2)
void sde_kernel(const float* __restrict__ in_signal,   // (B,16,512)
                const float* __restrict__ x0v,         // (B,32)
                const float* __restrict__ noise,       // (511,B,32)
                const float* __restrict__ Wf1, const float* __restrict__ bf1,
                const float* __restrict__ Wf2, const float* __restrict__ bf2,
                const float* __restrict__ Wg1, const float* __restrict__ bg1,
                const float* __restrict__ Wg2, const float* __restrict__ bg2,
                float* __restrict__ out)               // (B,32,512)
{
    const int lane = threadIdx.x;   // 0..63
    const int b    = blockIdx.x;    // batch row

    __shared__ __align__(16) float hbuf[2][128];   // [parity][hf(64), hg(64)]
    __shared__ __align__(16) float xbuf[32];       // broadcast x-state
    __shared__ __align__(16) float abuf[2][4][16]; // [quad parity][tt][k]

    // ---- weights -> registers (one-time, coalesced) ----
    float w1f[48], w1g[48];
#pragma unroll
    for (int k = 0; k < 48; ++k) {
        w1f[k] = Wf1[k * 64 + lane];
        w1g[k] = Wg1[k * 64 + lane];
    }
    float w2[64];
    const float* W2p = (lane < 32) ? (Wf2 + lane) : (Wg2 + (lane - 32));
#pragma unroll
    for (int j = 0; j < 64; ++j) w2[j] = W2p[j * 32];

    const float b1f = bf1[lane];
    const float b1g = bg1[lane];
    const float b2  = (lane < 32) ? bf2[lane] : bg2[lane - 32];

    // ---- state init ----
    float x_init = x0v[b * 32 + (lane & 31)];
    if (lane < 32) xbuf[lane] = x_init;

    const float* hsrc0 = hbuf[0] + ((lane >> 5) << 6);   // hf or hg, parity 0
    const float* hsrc1 = hbuf[1] + ((lane >> 5) << 6);   // parity 1
    const float* a_base = in_signal + ((size_t)(b * 16 + (lane & 15)) << 9);
    const float* noise_lane = noise + (size_t)b * 32 + (lane & 31);
    float* out_ptr = out + ((size_t)b * 32 + (lane & 31)) * 512;

    // prefetch eps two steps ahead
    float eps_c = noise_lane[0];                 // t = 0
    float eps_n = noise_lane[65536];             // t = 1

    {   // quad 0 a-values -> abuf[0] (transposed by lanes 0-15)
        float4 a0 = *(const float4*)(a_base);
        if (lane < 16) {
            abuf[0][0][lane] = a0.x;
            abuf[0][1][lane] = a0.y;
            abuf[0][2][lane] = a0.z;
            abuf[0][3][lane] = a0.w;
        }
    }
    float xq[4];
    xq[0] = x_init;
    wave_sync();

#define STEP(tt) do {                                                           \
    const int t_ = tq4 + (tt);                                                  \
    /* prefetch eps for step t+2 (~2 steps of latency cover) */                 \
    int tf_ = t_ + 2; if (tf_ > 510) tf_ = 510;                                 \
    float eps_f = noise_lane[(size_t)tf_ << 16];                                \
    /* layer-1 operands via LDS broadcast reads (no readlane) */                \
    float sa[16], sx[32];                                                       \
    *(float4*)&sa[0]  = *(const float4*)&ab_[tt][0];                            \
    *(float4*)&sa[4]  = *(const float4*)&ab_[tt][4];                            \
    *(float4*)&sa[8]  = *(const float4*)&ab_[tt][8];                            \
    *(float4*)&sa[12] = *(const float4*)&ab_[tt][12];                           \
    _Pragma("unroll")                                                           \
    for (int q = 0; q < 8; ++q)                                                 \
        *(float4*)&sx[q * 4] = *(const float4*)&xbuf[q * 4];                    \
    /* layer 1: lane j -> hf_j, hg_j ; dual accumulator chains */               \
    float accf0 = b1f, accf1 = 0.f, accg0 = b1g, accg1 = 0.f;                   \
    _Pragma("unroll")                                                           \
    for (int k = 0; k < 16; k += 2) {                                           \
        accf0 = fmaf(sa[k],     w1f[k],     accf0);                             \
        accg0 = fmaf(sa[k],     w1g[k],     accg0);                             \
        accf1 = fmaf(sa[k + 1], w1f[k + 1], accf1);                             \
        accg1 = fmaf(sa[k + 1], w1g[k + 1], accg1);                             \
    }                                                                           \
    _Pragma("unroll")                                                           \
    for (int i = 0; i < 32; i += 2) {                                           \
        accf0 = fmaf(sx[i],     w1f[16 + i], accf0);                            \
        accg0 = fmaf(sx[i],     w1g[16 + i], accg0);                            \
        accf1 = fmaf(sx[i + 1], w1f[17 + i], accf1);                            \
        accg1 = fmaf(sx[i + 1], w1g[17 + i], accg1);                            \
    }                                                                           \
    float hfv = fast_tanh(accf0 + accf1);                                       \
    float hgv = fast_tanh(accg0 + accg1);                                       \
    hbuf[(tt) & 1][lane]      = hfv;                                            \
    hbuf[(tt) & 1][64 + lane] = hgv;                                            \
    wave_sync();                                                                \
    /* layer 2: lanes 0-31 drift_i (hf), lanes 32-63 diff-pre_i (hg) */         \
    {                                                                           \
        const float* hs_ = ((tt) & 1) ? hsrc1 : hsrc0;                          \
        float acc2a = b2, acc2b = 0.f;                                          \
        _Pragma("unroll")                                                       \
        for (int j0 = 0; j0 < 64; j0 += 8) {                                    \
            const float4 ha = *(const float4*)&hs_[j0];                         \
            const float4 hb = *(const float4*)&hs_[j0 + 4];                     \
            acc2a = fmaf(ha.x, w2[j0 + 0], acc2a);                              \
            acc2b = fmaf(hb.x, w2[j0 + 4], acc2b);                              \
            acc2a = fmaf(ha.y, w2[j0 + 1], acc2a);                              \
            acc2b = fmaf(hb.y, w2[j0 + 5], acc2b);                              \
            acc2a = fmaf(ha.z, w2[j0 + 2], acc2a);                              \
            acc2b = fmaf(hb.z, w2[j0 + 6], acc2b);                              \
            acc2a = fmaf(ha.w, w2[j0 + 3], acc2a);                              \
            acc2b = fmaf(hb.w, w2[j0 + 7], acc2b);                              \
        }                                                                       \
        float acc2 = acc2a + acc2b;                                             \
        float other = __shfl_xor(acc2, 32, 64);                                 \
        float drift = (lane < 32) ? acc2 : other;                               \
        float gpre  = (lane < 32) ? other : acc2;                               \
        float xi = fmaf(gpre, eps_c * SQRT_DT_F, drift);                        \
        xi = fminf(5.0f, fmaxf(-5.0f, xi));                                     \
        if (lane < 32) xbuf[lane] = xi;   /* early write: covered by next     */\
        xq[((tt) + 1) & 3] = xi;          /* step's a-reads + a-FMAs          */\
        if ((tt) == 2) {                                                        \
            if (lane < 32)                                                      \
                *(float4*)(out_ptr + tq4) =                                     \
                    make_float4(xq[0], xq[1], xq[2], xq[3]);                    \
        }                                                                       \
    }                                                                           \
    wave_sync();                                                                \
    eps_c = eps_n; eps_n = eps_f;                                               \
} while (0)

    // main: t = 0..507 (127 quads)
    for (int tq = 0; tq < 127; ++tq) {
        const int tq4 = tq * 4;
        const float (*ab_)[16] = abuf[tq & 1];
        float4 aq_n = *(const float4*)(a_base + tq4 + 4);   // quad tq+1
        STEP(0);
        // stage next quad's a-values (parity flip; current quad reads ab_)
        if (lane < 16) {
            float (*abn)[16] = abuf[(tq + 1) & 1];
            abn[0][lane] = aq_n.x;
            abn[1][lane] = aq_n.y;
            abn[2][lane] = aq_n.z;
            abn[3][lane] = aq_n.w;
        }
        STEP(1); STEP(2); STEP(3);
    }
    // tail: t = 508, 509, 510  (store of [508..511] fires at tt==2)
    {
        const int tq4 = 508;
        const float (*ab_)[16] = abuf[127 & 1];
        STEP(0); STEP(1); STEP(2);
    }
#undef STEP
}

extern "C" void kernel_launch(void* const* d_in, const int* in_sizes, int n_in,
                              void* d_out, int out_size, void* d_ws, size_t ws_size,
                              hipStream_t stream) {
    // inputs: 0 ts(unused), 1 in_signal, 2 x0, 3 noise, 4 Wf1, 5 bf1, 6 Wf2,
    //         7 bf2, 8 Wg1, 9 bg1, 10 Wg2, 11 bg2
    const float* in_signal = (const float*)d_in[1];
    const float* x0v   = (const float*)d_in[2];
    const float* noise = (const float*)d_in[3];
    const float* Wf1 = (const float*)d_in[4];
    const float* bf1 = (const float*)d_in[5];
    const float* Wf2 = (const float*)d_in[6];
    const float* bf2 = (const float*)d_in[7];
    const float* Wg1 = (const float*)d_in[8];
    const float* bg1 = (const float*)d_in[9];
    const float* Wg2 = (const float*)d_in[10];
    const float* bg2 = (const float*)d_in[11];
    float* out = (float*)d_out;

    hipLaunchKernelGGL(sde_kernel, dim3(2048), dim3(64), 0, stream,
                       in_signal, x0v, noise, Wf1, bf1, Wf2, bf2,
                       Wg1, bg1, Wg2, bg2, out);
}